// Round 9
// baseline (73.808 us; speedup 1.0000x reference)
//
#include <hip/hip_runtime.h>
#include <math.h>

#define BB 2
#define CC 192
#define NN 16384
#define KK 16
#define COUT 192
#define MM (BB * NN)          // 32768 points
#define KDIM (2 * CC)         // 384 = GEMM K
#define EPSF 1e-5f
#define NGB 256               // gemm grid (partial-sum rows)

typedef __attribute__((ext_vector_type(8))) short short8;
typedef __attribute__((ext_vector_type(4))) float f32x4;

#define AS1P const __attribute__((address_space(1))) void*
#define AS3P __attribute__((address_space(3))) void*

static __device__ __forceinline__ float bf16_to_f32(unsigned int u16) {
    return __uint_as_float(u16 << 16);
}
static __device__ __forceinline__ float bf16hi_to_f32(unsigned int u) {
    return __uint_as_float(u & 0xffff0000u);
}
static __device__ __forceinline__ unsigned short f32_to_bf16(float f) {
    unsigned int u = __float_as_uint(f);
    unsigned int r = (u + 0x7fffu + ((u >> 16) & 1u)) >> 16;  // RNE
    return (unsigned short)r;
}
static __device__ __forceinline__ float gelu_exact(float v) {
    return 0.5f * v * (1.0f + erff(v * 0.70710678118654752440f));
}

// ---------------------------------------------------------------------------
// Kernel 1 (k_prep): blockIdx < 3072 -> transpose+cast x [B,C,N] f32 ->
// xt4 [b][chunk][n][48] bf16 (4 channel-chunks of 48, each a contiguous
// 1.57 MB sub-table so one chunk fits a per-XCD L2). blockIdx >= 3072 ->
// cast W -> bf16.
// ---------------------------------------------------------------------------
#define TRB (512 * 3 * BB)   // 3072 transpose blocks
__global__ __launch_bounds__(256) void k_prep(const float* __restrict__ x,
                                              unsigned int* __restrict__ xt32,
                                              const float* __restrict__ W,
                                              unsigned short* __restrict__ Wb) {
    int bid = blockIdx.x;
    int t = threadIdx.x;
    if (bid >= TRB) {
        int wb = bid - TRB;                       // 0..71
        int base = wb * 1024 + t * 4;
        float4 v = *(const float4*)(W + base);
        uint2 o;
        o.x = (unsigned int)f32_to_bf16(v.x) | ((unsigned int)f32_to_bf16(v.y) << 16);
        o.y = (unsigned int)f32_to_bf16(v.z) | ((unsigned int)f32_to_bf16(v.w) << 16);
        *(uint2*)(Wb + base) = o;
        return;
    }
    __shared__ float tile[64][33];
    int nb = bid & 511;
    int rest = bid >> 9;
    int cb = rest % 3;
    int b = rest / 3;
    int n0 = nb * 32, c0 = cb * 64;
    int tx = t & 31, ty = t >> 5;  // (32,8)
    #pragma unroll
    for (int j = 0; j < 64; j += 8)
        tile[ty + j][tx] = x[((size_t)b * CC + (c0 + ty + j)) * NN + n0 + tx];
    __syncthreads();
    int c = c0 + 2 * tx;           // even; pair (c, c+1) stays in one chunk
    int chunk = c / 48, wi = c % 48;
    #pragma unroll
    for (int j = 0; j < 32; j += 8) {
        int n = n0 + ty + j;
        unsigned int w = (unsigned int)f32_to_bf16(tile[2 * tx][ty + j]) |
                         ((unsigned int)f32_to_bf16(tile[2 * tx + 1][ty + j]) << 16);
        xt32[((size_t)(b * 4 + chunk) * NN + n) * 24 + wi / 2] = w;
    }
}

// ---------------------------------------------------------------------------
// Kernel 2 (k_gather): L2-resident channel-chunked gather.
// combo = blockIdx.x & 7 -> (b, chunk); standard round-robin dispatch pins
// each combo to one XCD, whose 1.57 MB sub-table then lives in that XCD's L2.
// Block: 384 threads = 64 points x 6 lanes (8 channels per lane, uint4 row
// reads). Output xcat[m][2c] = {xs_c, mr_c} interleaved bf16 (GEMM A layout,
// unchanged from round 8).
// ---------------------------------------------------------------------------
__global__ __launch_bounds__(384) void k_gather(const unsigned short* __restrict__ xt4,
                                                const int* __restrict__ edge,
                                                uint4* __restrict__ xcat4) {
    __shared__ int sj[64 * KK], si[64 * KK];
    int bid = blockIdx.x;
    int combo = bid & 7;           // -> XCD (perf heuristic only)
    int g = bid >> 3;              // 0..255 point-group
    int b = combo >> 2, ch = combo & 3;
    int n0 = g * 64;
    int t = threadIdx.x;
    const int* ej = edge + ((size_t)b * NN + n0) * KK;
    const int* ei = edge + ((size_t)(BB + b) * NN + n0) * KK;
    for (int u = t; u < 64 * KK; u += 384) { sj[u] = ej[u]; si[u] = ei[u]; }
    __syncthreads();

    int p = t / 6, c4 = t % 6;     // point, uint4-slot (8 channels)
    const uint4* base = (const uint4*)(xt4 + (size_t)(b * 4 + ch) * NN * 48) + c4;
    float mx[8];
    #pragma unroll
    for (int c = 0; c < 8; ++c) mx[c] = -INFINITY;
    #pragma unroll
    for (int k = 0; k < KK; ++k) {
        uint4 vj = base[(size_t)sj[p * KK + k] * 6];
        uint4 vi = base[(size_t)si[p * KK + k] * 6];
        const unsigned int dj[4] = {vj.x, vj.y, vj.z, vj.w};
        const unsigned int di[4] = {vi.x, vi.y, vi.z, vi.w};
        #pragma unroll
        for (int d = 0; d < 4; ++d) {
            mx[2 * d]     = fmaxf(mx[2 * d],     bf16_to_f32(dj[d] & 0xffffu) - bf16_to_f32(di[d] & 0xffffu));
            mx[2 * d + 1] = fmaxf(mx[2 * d + 1], bf16hi_to_f32(dj[d]) - bf16hi_to_f32(di[d]));
        }
    }
    uint4 xs = base[(size_t)(n0 + p) * 6];
    uint4 o0, o1;
    o0.x = (xs.x & 0xffffu) | ((unsigned int)f32_to_bf16(mx[0]) << 16);
    o0.y = (xs.x >> 16)     | ((unsigned int)f32_to_bf16(mx[1]) << 16);
    o0.z = (xs.y & 0xffffu) | ((unsigned int)f32_to_bf16(mx[2]) << 16);
    o0.w = (xs.y >> 16)     | ((unsigned int)f32_to_bf16(mx[3]) << 16);
    o1.x = (xs.z & 0xffffu) | ((unsigned int)f32_to_bf16(mx[4]) << 16);
    o1.y = (xs.z >> 16)     | ((unsigned int)f32_to_bf16(mx[5]) << 16);
    o1.z = (xs.w & 0xffffu) | ((unsigned int)f32_to_bf16(mx[6]) << 16);
    o1.w = (xs.w >> 16)     | ((unsigned int)f32_to_bf16(mx[7]) << 16);
    size_t orow = (size_t)(b * NN + n0 + p) * 48;
    xcat4[orow + ch * 12 + 2 * c4]     = o0;
    xcat4[orow + ch * 12 + 2 * c4 + 1] = o1;
}

// ---------------------------------------------------------------------------
// Kernel 3 (k_gemm): MFMA GEMM h[m][o] = sum_k xcat[m][k]*Wb[o][k].
// global_load_lds width=16 staging: linear LDS dest + inverse-swizzled global
// source; swizzled ds_read_b128 compute reads. (Unchanged from round 8.)
// ---------------------------------------------------------------------------
#define BMT 128
__global__ __launch_bounds__(512) void k_gemm(const unsigned short* __restrict__ xcat,
                                              const unsigned short* __restrict__ Wb,
                                              unsigned short* __restrict__ h,
                                              float* __restrict__ psum,
                                              float* __restrict__ psum2) {
    __shared__ __align__(16) char ldsA[BMT * 128];    // 16 KB (reused for reduce)
    __shared__ __align__(16) char ldsB[COUT * 128];   // 24 KB
    int t = threadIdx.x;
    int m0 = blockIdx.x * BMT;
    int w = t >> 6, l = t & 63, lo = l & 15, q4 = l >> 4;
    int lr = l >> 3, lc = l & 7;   // staging: row-in-8-group, chunk
    f32x4 acc[12];
    #pragma unroll
    for (int i = 0; i < 12; ++i) acc[i] = (f32x4){0.f, 0.f, 0.f, 0.f};
    int rA = w * 16 + lo;

    for (int ks = 0; ks < KDIM / 64; ++ks) {
        int k0 = ks * 64;
        if (ks) __syncthreads();
        #pragma unroll
        for (int e = 0; e < 2; ++e) {
            int r = w * 16 + e * 8 + lr;
            int cg = lc ^ (r & 7);
            const unsigned short* gp = xcat + (size_t)(m0 + r) * KDIM + k0 + cg * 8;
            __builtin_amdgcn_global_load_lds((AS1P)gp, (AS3P)(ldsA + w * 2048 + e * 1024), 16, 0, 0);
        }
        #pragma unroll
        for (int e = 0; e < 3; ++e) {
            int r = w * 24 + e * 8 + lr;
            int cg = lc ^ (r & 7);
            const unsigned short* gp = Wb + (size_t)r * KDIM + k0 + cg * 8;
            __builtin_amdgcn_global_load_lds((AS1P)gp, (AS3P)(ldsB + w * 3072 + e * 1024), 16, 0, 0);
        }
        __syncthreads();
        #pragma unroll
        for (int kh = 0; kh < 2; ++kh) {
            int cb = kh * 64 + q4 * 16;
            short8 a = *(const short8*)(ldsA + rA * 128 + (cb ^ ((rA & 7) << 4)));
            #pragma unroll
            for (int ot = 0; ot < 12; ++ot) {
                int rB = ot * 16 + lo;
                short8 bf = *(const short8*)(ldsB + rB * 128 + (cb ^ ((rB & 7) << 4)));
                acc[ot] = __builtin_amdgcn_mfma_f32_16x16x32_bf16(a, bf, acc[ot], 0, 0, 0);
            }
        }
    }
    __syncthreads();  // all waves done with ldsA before the reduce overlay

    float* reds = (float*)ldsA;              // [8][COUT]
    float* reds2 = reds + 8 * COUT;          // [8][COUT]
    int mrow = m0 + w * 16 + q4 * 4;
    #pragma unroll
    for (int ot = 0; ot < 12; ++ot) {
        int o = ot * 16 + lo;
        float s = 0.f, s2 = 0.f;
        #pragma unroll
        for (int r = 0; r < 4; ++r) {
            float v = acc[ot][r];
            h[(size_t)(mrow + r) * COUT + o] = f32_to_bf16(v);
            s += v;
            s2 += v * v;
        }
        s += __shfl_xor(s, 16);  s2 += __shfl_xor(s2, 16);
        s += __shfl_xor(s, 32);  s2 += __shfl_xor(s2, 32);
        if (q4 == 0) {
            reds[w * COUT + o] = s;
            reds2[w * COUT + o] = s2;
        }
    }
    __syncthreads();
    if (t < COUT) {
        float a = 0.f, a2 = 0.f;
        #pragma unroll
        for (int w8 = 0; w8 < 8; ++w8) {
            a += reds[w8 * COUT + t];
            a2 += reds2[w8 * COUT + t];
        }
        psum[blockIdx.x * COUT + t] = a;
        psum2[blockIdx.x * COUT + t] = a2;
    }
}

// ---------------------------------------------------------------------------
// Kernel 4 (k_bn): parallel partial reduce. 24 blocks x 256 threads.
// ---------------------------------------------------------------------------
__global__ __launch_bounds__(256) void k_bn(const float* __restrict__ psum,
                                            const float* __restrict__ psum2,
                                            const float* __restrict__ gamma,
                                            const float* __restrict__ beta,
                                            float* __restrict__ sc_sh) {
    __shared__ float red[2][32][8];
    int t = threadIdx.x;
    int ch = t & 7, rr = t >> 3;
    int o = blockIdx.x * 8 + ch;
    float a = 0.f, a2 = 0.f;
    for (int r = rr; r < NGB; r += 32) {
        a += psum[r * COUT + o];
        a2 += psum2[r * COUT + o];
    }
    red[0][rr][ch] = a;
    red[1][rr][ch] = a2;
    __syncthreads();
    if (t < 8) {
        float s = 0.f, s2 = 0.f;
        #pragma unroll
        for (int i = 0; i < 32; ++i) { s += red[0][i][t]; s2 += red[1][i][t]; }
        int oo = blockIdx.x * 8 + t;
        float inv_m = 1.0f / (float)MM;
        float mean = s * inv_m;
        float var = s2 * inv_m - mean * mean;
        float sc = gamma[oo] * rsqrtf(var + EPSF);
        sc_sh[oo] = sc;
        sc_sh[COUT + oo] = beta[oo] - mean * sc;
    }
}

// ---------------------------------------------------------------------------
// Kernel 5 (k_out): BN apply + exact GELU + transpose h [m][o] -> out [B,O,N].
// Vectorized: uint4 h-loads (8 ch/thread), float4 out-stores (G13).
// Block: 64 n x 32 o, 256 threads.
// ---------------------------------------------------------------------------
__global__ __launch_bounds__(256) void k_out(const unsigned short* __restrict__ h,
                                             const float* __restrict__ sc_sh,
                                             float* __restrict__ out) {
    __shared__ float tile[64][36];   // stride 36 floats: 16B-aligned rows
    int b = blockIdx.z;
    int n0 = blockIdx.x * 64;        // NN/64 = 256
    int o0 = blockIdx.y * 32;        // COUT/32 = 6
    int t = threadIdx.x;
    {
        int r = t >> 2, c4 = t & 3;  // row 0..63, uint4 slot (8 channels)
        uint4 hv = *(const uint4*)(h + ((size_t)b * NN + n0 + r) * COUT + o0 + c4 * 8);
        const unsigned int d[4] = {hv.x, hv.y, hv.z, hv.w};
        #pragma unroll
        for (int e = 0; e < 4; ++e) {
            int oc = c4 * 8 + 2 * e;
            float v0 = bf16_to_f32(d[e] & 0xffffu) * sc_sh[o0 + oc] + sc_sh[COUT + o0 + oc];
            float v1 = bf16hi_to_f32(d[e]) * sc_sh[o0 + oc + 1] + sc_sh[COUT + o0 + oc + 1];
            tile[r][oc] = gelu_exact(v0);
            tile[r][oc + 1] = gelu_exact(v1);
        }
    }
    __syncthreads();
    int o = t >> 3, q = t & 7;       // o row, float4-quad along n
    #pragma unroll
    for (int it = 0; it < 2; ++it) {
        int nn = q * 4 + it * 32;
        float4 v = {tile[nn][o], tile[nn + 1][o], tile[nn + 2][o], tile[nn + 3][o]};
        *(float4*)(out + ((size_t)b * COUT + o0 + o) * NN + n0 + nn) = v;
    }
}

// ---------------------------------------------------------------------------
extern "C" void kernel_launch(void* const* d_in, const int* in_sizes, int n_in,
                              void* d_out, int out_size, void* d_ws, size_t ws_size,
                              hipStream_t stream) {
    const float* x = (const float*)d_in[0];
    const float* W = (const float*)d_in[1];
    // d_in[2] = b_conv: cancels in training-mode BN
    const float* gamma = (const float*)d_in[3];
    const float* beta = (const float*)d_in[4];
    const int* edge = (const int*)d_in[5];
    float* out = (float*)d_out;

    char* ws = (char*)d_ws;
    unsigned short* xt4 = (unsigned short*)ws;                // [B][4][N][48] bf16
    ws += (size_t)MM * CC * 2;
    unsigned short* xcat = (unsigned short*)ws;               // [M][2C] bf16
    ws += (size_t)MM * KDIM * 2;
    unsigned short* Wb = (unsigned short*)ws;                 // [COUT][2C] bf16
    ws += (size_t)COUT * KDIM * 2;
    unsigned short* h = (unsigned short*)ws;                  // [M][COUT] bf16
    ws += (size_t)MM * COUT * 2;
    float* psum = (float*)ws;                                 // [NGB][COUT]
    ws += (size_t)NGB * COUT * sizeof(float);
    float* psum2 = (float*)ws;                                // [NGB][COUT]
    ws += (size_t)NGB * COUT * sizeof(float);
    float* sc_sh = (float*)ws;                                // [2*COUT]

    k_prep<<<TRB + 72, 256, 0, stream>>>(x, (unsigned int*)xt4, W, Wb);

    k_gather<<<8 * (NN / 64), 384, 0, stream>>>(xt4, edge, (uint4*)xcat);

    k_gemm<<<MM / BMT, 512, 0, stream>>>(xcat, Wb, h, psum, psum2);

    k_bn<<<24, 256, 0, stream>>>(psum, psum2, gamma, beta, sc_sh);

    dim3 ogrid(NN / 64, COUT / 32, BB);
    k_out<<<ogrid, dim3(256), 0, stream>>>(h, sc_sh, out);
}